// Round 1
// baseline (131.612 us; speedup 1.0000x reference)
//
#include <hip/hip_runtime.h>

// Raymarcher (MVP-style): B=1, H=W=128 (R=16384 rays), NSTEPS=64, K=32 prims,
// template (K,4,16,16,16) fp32. Output: rgb(3R) | alpha(R) | rgba(4R) fp32.
//
// Strategy: 8 threads/ray (4 prims each), shfl_xor reduction per step,
// per-(ray,prim) slab-interval precull (conservative, widened 1e-3 in y-space;
// exact reference inside-test still applied), early exit on t>=tmax / alpha>=1.

namespace {

constexpr float kDT    = 1.0f / 64.0f;
constexpr int   kSteps = 64;
constexpr int   kTPR   = 8;   // threads per ray
constexpr int   kKPL   = 4;   // prims per lane (32 / 8)

__global__ __launch_bounds__(256) void raymarch(
    const float* __restrict__ raypos,    // R*3
    const float* __restrict__ raydir,    // R*3
    const float* __restrict__ tminmax,   // R*2
    const float* __restrict__ primpos,   // 32*3
    const float* __restrict__ primrot,   // 32*3*3 (k,i,j)
    const float* __restrict__ primscale, // 32*3
    const float* __restrict__ tmpl,      // 32*4*16*16*16
    float* __restrict__ out,             // 8*R
    int R)
{
    const int tid = threadIdx.x;
    const int pg  = tid & (kTPR - 1);
    const int ray = blockIdx.x * (blockDim.x / kTPR) + (tid >> 3);
    if (ray >= R) return;

    const float rpx = raypos[ray * 3 + 0];
    const float rpy = raypos[ray * 3 + 1];
    const float rpz = raypos[ray * 3 + 2];
    const float rdx = raydir[ray * 3 + 0];
    const float rdy = raydir[ray * 3 + 1];
    const float rdz = raydir[ray * 3 + 2];
    const float tmin = tminmax[ray * 2 + 0];
    const float tmax = tminmax[ray * 2 + 1];

    // Per-lane primitive constants in registers.
    float ppx[kKPL], ppy[kKPL], ppz[kKPL];
    float rot[kKPL][9];
    float sc[kKPL][3];
    float tlo[kKPL], thi[kKPL];

    #pragma unroll
    for (int kk = 0; kk < kKPL; ++kk) {
        const int k = pg * kKPL + kk;
        ppx[kk] = primpos[k * 3 + 0];
        ppy[kk] = primpos[k * 3 + 1];
        ppz[kk] = primpos[k * 3 + 2];
        #pragma unroll
        for (int j = 0; j < 9; ++j) rot[kk][j] = primrot[k * 9 + j];
        sc[kk][0] = primscale[k * 3 + 0];
        sc[kk][1] = primscale[k * 3 + 1];
        sc[kk][2] = primscale[k * 3 + 2];

        // Slab test: y_i(t) = a_i + d_i * t, inside iff |y_i| <= 1 (widened).
        const float ox = rpx - ppx[kk], oy = rpy - ppy[kk], oz = rpz - ppz[kk];
        float lo = -1e30f, hi = 1e30f;
        #pragma unroll
        for (int i = 0; i < 3; ++i) {
            const float a = (rot[kk][3*i+0]*ox + rot[kk][3*i+1]*oy + rot[kk][3*i+2]*oz) * sc[kk][i];
            const float d = (rot[kk][3*i+0]*rdx + rot[kk][3*i+1]*rdy + rot[kk][3*i+2]*rdz) * sc[kk][i];
            const float inv = 1.0f / d;
            const float tA = (-1.001f - a) * inv;
            const float tB = ( 1.001f - a) * inv;
            lo = fmaxf(lo, fminf(tA, tB));
            hi = fminf(hi, fmaxf(tA, tB));
        }
        tlo[kk] = lo;
        thi[kk] = hi;
    }

    float rgb0 = 0.f, rgb1 = 0.f, rgb2 = 0.f, alpha = 0.f;

    for (int i = 0; i < kSteps; ++i) {
        const float t = fmaf((float)i, kDT, tmin);
        if (t >= tmax) break;  // valid=0 from here on -> contrib=0 forever

        const float px = fmaf(rdx, t, rpx);
        const float py = fmaf(rdy, t, rpy);
        const float pz = fmaf(rdz, t, rpz);

        float s[4] = {0.f, 0.f, 0.f, 0.f};

        #pragma unroll
        for (int kk = 0; kk < kKPL; ++kk) {
            if (t < tlo[kk] || t > thi[kk]) continue;
            const float xlx = px - ppx[kk];
            const float xly = py - ppy[kk];
            const float xlz = pz - ppz[kk];
            const float y0 = (rot[kk][0]*xlx + rot[kk][1]*xly + rot[kk][2]*xlz) * sc[kk][0];
            const float y1 = (rot[kk][3]*xlx + rot[kk][4]*xly + rot[kk][5]*xlz) * sc[kk][1];
            const float y2 = (rot[kk][6]*xlx + rot[kk][7]*xly + rot[kk][8]*xlz) * sc[kk][2];
            if (fabsf(y0) <= 1.0f && fabsf(y1) <= 1.0f && fabsf(y2) <= 1.0f) {
                // Trilinear sample. g in [0,15] guaranteed by inside test.
                const float gz = (y0 + 1.0f) * 7.5f;
                const float gy = (y1 + 1.0f) * 7.5f;
                const float gx = (y2 + 1.0f) * 7.5f;
                const int iz = (int)fminf(floorf(gz), 14.0f);
                const int iy = (int)fminf(floorf(gy), 14.0f);
                const int ix = (int)fminf(floorf(gx), 14.0f);
                const float fz = fminf(gz - (float)iz, 1.0f);
                const float fy = fminf(gy - (float)iy, 1.0f);
                const float fx = fminf(gx - (float)ix, 1.0f);
                const float oz_ = 1.0f - fz, oy_ = 1.0f - fy, ox_ = 1.0f - fx;
                const float w000 = oz_ * oy_ * ox_;
                const float w001 = oz_ * oy_ * fx;
                const float w010 = oz_ * fy  * ox_;
                const float w011 = oz_ * fy  * fx;
                const float w100 = fz  * oy_ * ox_;
                const float w101 = fz  * oy_ * fx;
                const float w110 = fz  * fy  * ox_;
                const float w111 = fz  * fy  * fx;
                const int k = pg * kKPL + kk;
                const float* tp = tmpl + k * 16384 + iz * 256 + iy * 16 + ix;
                #pragma unroll
                for (int c = 0; c < 4; ++c) {
                    const float* tc = tp + c * 4096;
                    const float v = w000 * tc[0]   + w001 * tc[1]
                                  + w010 * tc[16]  + w011 * tc[17]
                                  + w100 * tc[256] + w101 * tc[257]
                                  + w110 * tc[272] + w111 * tc[273];
                    s[c] += v;
                }
            }
        }

        // Reduce the 4 partial sums across the 8 lanes of this ray.
        #pragma unroll
        for (int m = 1; m < kTPR; m <<= 1) {
            s[0] += __shfl_xor(s[0], m);
            s[1] += __shfl_xor(s[1], m);
            s[2] += __shfl_xor(s[2], m);
            s[3] += __shfl_xor(s[3], m);
        }

        const float na = fminf(fmaxf(fmaf(s[3], kDT, alpha), 0.0f), 1.0f);
        const float contrib = na - alpha;
        rgb0 = fmaf(s[0], contrib, rgb0);
        rgb1 = fmaf(s[1], contrib, rgb1);
        rgb2 = fmaf(s[2], contrib, rgb2);
        alpha = na;
        if (alpha >= 1.0f) break;  // salpha >= 0 -> contrib=0 forever
    }

    if (pg == 0) {
        // rayrgb (3,R)
        out[0 * R + ray] = rgb0;
        out[1 * R + ray] = rgb1;
        out[2 * R + ray] = rgb2;
        // rayalpha (1,R)
        out[3 * R + ray] = alpha;
        // rayrgba (4,R)
        out[4 * R + ray] = rgb0;
        out[5 * R + ray] = rgb1;
        out[6 * R + ray] = rgb2;
        out[7 * R + ray] = alpha;
    }
}

} // namespace

extern "C" void kernel_launch(void* const* d_in, const int* in_sizes, int n_in,
                              void* d_out, int out_size, void* d_ws, size_t ws_size,
                              hipStream_t stream) {
    const float* raypos    = (const float*)d_in[0];
    const float* raydir    = (const float*)d_in[1];
    const float* tminmax   = (const float*)d_in[2];
    const float* primpos   = (const float*)d_in[3];
    const float* primrot   = (const float*)d_in[4];
    const float* primscale = (const float*)d_in[5];
    const float* tmpl      = (const float*)d_in[6];
    float* out = (float*)d_out;

    const int R = in_sizes[0] / 3;                 // 16384
    const int raysPerBlock = 256 / kTPR;           // 32
    const int grid = (R + raysPerBlock - 1) / raysPerBlock;

    raymarch<<<dim3(grid), dim3(256), 0, stream>>>(
        raypos, raydir, tminmax, primpos, primrot, primscale, tmpl, out, R);
}